// Round 10
// baseline (188.948 us; speedup 1.0000x reference)
//
#include <hip/hip_runtime.h>
#include <math.h>

#define NATOMS  512
#define MROWS   64
#define BATCH   65536
#define BT      8           // batch columns per block (8 waves, 1 col/wave)
#define NSPARSE 5
#define DEPSF   1e-6f

typedef float v2f __attribute__((ext_vector_type(2)));

// ---------------------------------------------------------------------------
// prep: gram = D^T D (f64 accumulate -> f32). 1024 blocks x 256 threads.
// ---------------------------------------------------------------------------
__global__ void ksvd_prep(const float* __restrict__ D,
                          float* __restrict__ gram) {
  const int idx = blockIdx.x * 256 + threadIdx.x;     // 0 .. 512*512-1
  const int i = idx >> 9;
  const int j = idx & (NATOMS - 1);
  double acc = 0.0;
#pragma unroll 8
  for (int m = 0; m < MROWS; ++m)
    acc += (double)D[m * NATOMS + i] * (double)D[m * NATOMS + j];
  gram[idx] = (float)acc;
}

// ---------------------------------------------------------------------------
// wave64 max-reduce on the VALU via DPP (no LDS ops, no lgkmcnt waits).
// bound_ctrl=true feeds 0 for shifted-out lanes: harmless, keys are >= 0.
// ---------------------------------------------------------------------------
__device__ __forceinline__ float wave_max_nonneg(float x) {
  int v = __builtin_bit_cast(int, x);
#define DPP_MAX_STEP(ctrl)                                                   \
  {                                                                          \
    const int t = __builtin_amdgcn_update_dpp(0, v, (ctrl), 0xf, 0xf, true); \
    v = __builtin_bit_cast(                                                  \
        int, fmaxf(__builtin_bit_cast(float, v), __builtin_bit_cast(float, t))); \
  }
  DPP_MAX_STEP(0x111)   // row_shr:1
  DPP_MAX_STEP(0x112)   // row_shr:2
  DPP_MAX_STEP(0x114)   // row_shr:4
  DPP_MAX_STEP(0x118)   // row_shr:8
  DPP_MAX_STEP(0x142)   // row_bcast15
  DPP_MAX_STEP(0x143)   // row_bcast31
#undef DPP_MAX_STEP
  return __builtin_bit_cast(float, __builtin_amdgcn_readlane(v, 63));
}

// ---------------------------------------------------------------------------
// main: block = 8 waves = 8 batch columns (one per wave). Doubling the
// columns per block halves per-column phase-1 cost (D reads, X broadcast
// reads, addressing) at constant per-lane FMA: lane owns ONE atom
// (atom = wave*64+lane) and accumulates all 8 columns as 4 packed col-pairs
// (pk-fma over columns). Even/odd-m split accumulators keep the per-
// (atom,col) sum order bit-identical to rounds 4-9.
// Phase 2 is unchanged (per-wave OMP, all-f32, DPP argmax).
// LDS = union of X staging and dtx transpose -> 16 KB.
// ---------------------------------------------------------------------------
__global__ __launch_bounds__(512, 4) void ksvd_main(
    const float* __restrict__ X, const float* __restrict__ D,
    const float* __restrict__ gram, float* __restrict__ out) {
  __shared__ union {
    v2f   xs2[MROWS][BT / 2];        // 2 KB: col-pairs {x2j, x2j+1} per m
    float dtxT[BT][NATOMS];          // 16 KB: dtx transposed per column
  } sh;                              // -> 16384 B total

  const int t    = threadIdx.x;
  const int lane = t & 63;
  const int wave = t >> 6;                      // 0..7
  const int b0   = blockIdx.x * BT;

  // ---- stage X tile (64 m x 8 c) as col-pairs
  if (t < MROWS * (BT / 2)) {                   // 256 entries
    const int m = t >> 2, j = t & 3;
    v2f p;
    p.x = X[(size_t)m * BATCH + b0 + 2 * j];
    p.y = X[(size_t)m * BATCH + b0 + 2 * j + 1];
    sh.xs2[m][j] = p;
  }
  __syncthreads();

  // ---- phase 1: lane owns ONE atom; 8 columns as 4 packed col-pairs
  const int atom = wave * 64 + lane;            // 0..511
  v2f accA[4], accB[4];
#pragma unroll
  for (int j = 0; j < 4; ++j) {
    accA[j].x = 0.f; accA[j].y = 0.f;
    accB[j].x = 0.f; accB[j].y = 0.f;
  }

#pragma unroll 4
  for (int m = 0; m < MROWS; m += 2) {
    const float dA = D[m * NATOMS + atom];
    const float dB = D[(m + 1) * NATOMS + atom];
    const float4 fa0 = reinterpret_cast<const float4*>(&sh.xs2[m][0])[0];
    const float4 fa1 = reinterpret_cast<const float4*>(&sh.xs2[m][0])[1];
    const float4 fb0 = reinterpret_cast<const float4*>(&sh.xs2[m + 1][0])[0];
    const float4 fb1 = reinterpret_cast<const float4*>(&sh.xs2[m + 1][0])[1];
    v2f dA2; dA2.x = dA; dA2.y = dA;
    v2f dB2; dB2.x = dB; dB2.y = dB;
    v2f xv;
    xv.x = fa0.x; xv.y = fa0.y; accA[0] = __builtin_elementwise_fma(dA2, xv, accA[0]);
    xv.x = fa0.z; xv.y = fa0.w; accA[1] = __builtin_elementwise_fma(dA2, xv, accA[1]);
    xv.x = fa1.x; xv.y = fa1.y; accA[2] = __builtin_elementwise_fma(dA2, xv, accA[2]);
    xv.x = fa1.z; xv.y = fa1.w; accA[3] = __builtin_elementwise_fma(dA2, xv, accA[3]);
    xv.x = fb0.x; xv.y = fb0.y; accB[0] = __builtin_elementwise_fma(dB2, xv, accB[0]);
    xv.x = fb0.z; xv.y = fb0.w; accB[1] = __builtin_elementwise_fma(dB2, xv, accB[1]);
    xv.x = fb1.x; xv.y = fb1.y; accB[2] = __builtin_elementwise_fma(dB2, xv, accB[2]);
    xv.x = fb1.z; xv.y = fb1.w; accB[3] = __builtin_elementwise_fma(dB2, xv, accB[3]);
  }
  __syncthreads();   // all xs2 reads complete before dtxT overwrites the union

#pragma unroll
  for (int j = 0; j < 4; ++j) {
    const v2f s = accA[j] + accB[j];
    sh.dtxT[2 * j][atom]     = s.x;
    sh.dtxT[2 * j + 1][atom] = s.y;
  }
  __syncthreads();

  // ---- phase 2: this wave's column; lane owns 8 consecutive atoms 8l..8l+7
  const int cglob = b0 + wave;
  float dtxr[8];
  {
    const float4 f0 = *reinterpret_cast<const float4*>(&sh.dtxT[wave][8 * lane]);
    const float4 f1 = *reinterpret_cast<const float4*>(&sh.dtxT[wave][8 * lane + 4]);
    dtxr[0] = f0.x; dtxr[1] = f0.y; dtxr[2] = f0.z; dtxr[3] = f0.w;
    dtxr[4] = f1.x; dtxr[5] = f1.y; dtxr[6] = f1.z; dtxr[7] = f1.w;
  }

  int   idxs[NSPARSE];
  float rhsf[NSPARSE];
  float gc[NSPARSE - 1][8];                 // cached gram columns (f32)
  float L[NSPARSE][NSPARSE];                // lower-tri Cholesky (static idx)
  float inv_d[NSPARSE];
  float y[NSPARSE];
  float sol[NSPARSE];

#pragma unroll
  for (int k = 0; k < NSPARSE; ++k) {
    // corr = dtx - sum_s sol[s]*gc_s (f32); f32-key argmax, first-max ties
    float bv = -1.0f;
    int   bn = 0;
#pragma unroll
    for (int jj = 0; jj < 8; ++jj) {
      float cv = dtxr[jj];
#pragma unroll
      for (int s = 0; s < k; ++s) cv -= sol[s] * gc[s][jj];
      const float av = fabsf(cv);
      if (av > bv) { bv = av; bn = 8 * lane + jj; }   // strict >: first-max
    }
    // wave max on the VALU (DPP), then owner = lowest lane holding the max
    const float wmax = wave_max_nonneg(bv);
    const unsigned long long own = __ballot(bv == wmax);
    const int owner = __ffsll((long long)own) - 1;    // lowest lane: first-max
    const int idx = __builtin_amdgcn_readlane(bn, owner);  // uniform (SGPR)
    idxs[k] = idx;

    // gram column for future corr updates (vector, L2-resident)
    if (k < NSPARSE - 1) {
      const float4 g0 = *reinterpret_cast<const float4*>(
          &gram[(size_t)idx * NATOMS + 8 * lane]);
      const float4 g1 = *reinterpret_cast<const float4*>(
          &gram[(size_t)idx * NATOMS + 8 * lane + 4]);
      gc[k][0] = g0.x; gc[k][1] = g0.y; gc[k][2] = g0.z; gc[k][3] = g0.w;
      gc[k][4] = g1.x; gc[k][5] = g1.y; gc[k][6] = g1.z; gc[k][7] = g1.w;
    }

    // rhs: one uniform LDS read (broadcast)
    rhsf[k] = sh.dtxT[wave][idx];

    // Gram row k entries: uniform (scalar) loads
    float arowf[NSPARSE];
#pragma unroll
    for (int j = 0; j < k; ++j)
      arowf[j] = gram[(size_t)idx * NATOMS + idxs[j]];
    const float gdiag = gram[(size_t)idx * NATOMS + idx];

    // incremental Cholesky row k of (G_active + eps*I), rsqrtf-based
    float ss = gdiag + DEPSF;
#pragma unroll
    for (int j = 0; j < k; ++j) {
      float w = arowf[j];
#pragma unroll
      for (int tt = 0; tt < j; ++tt) w -= L[k][tt] * L[j][tt];
      w *= inv_d[j];
      L[k][j] = w;
      ss -= w * w;
    }
    const float inv = rsqrtf(ss);
    L[k][k]  = ss * inv;                    // = sqrt(ss)
    inv_d[k] = inv;

    // forward substitution: only y[k] is new (y[0..k-1] unchanged)
    {
      float s2 = rhsf[k];
#pragma unroll
      for (int j = 0; j < k; ++j) s2 -= L[k][j] * y[j];
      y[k] = s2 * inv;
    }
    // backward substitution (full, sol changes every round)
#pragma unroll
    for (int i = k; i >= 0; --i) {
      float s2 = y[i];
#pragma unroll
      for (int j = i + 1; j <= k; ++j) s2 -= L[j][i] * sol[j];
      sol[i] = s2 * inv_d[i];
    }
  }

  // ---- epilogue: scatter the 5 coefficients (out pre-zeroed by memset)
  if (lane == 0) {
#pragma unroll
    for (int s = 0; s < NSPARSE; ++s)
      out[(size_t)idxs[s] * BATCH + cglob] = sol[s];
  }
}

// ---------------------------------------------------------------------------
extern "C" void kernel_launch(void* const* d_in, const int* in_sizes, int n_in,
                              void* d_out, int out_size, void* d_ws,
                              size_t ws_size, hipStream_t stream) {
  (void)in_sizes; (void)n_in; (void)out_size; (void)ws_size;
  const float* X = (const float*)d_in[0];   // (64, 65536)
  const float* D = (const float*)d_in[1];   // (64, 512)
  float* out = (float*)d_out;               // (512, 65536)
  float* gram = (float*)d_ws;               // 1 MB scratch

  ksvd_prep<<<(NATOMS * NATOMS) / 256, 256, 0, stream>>>(D, gram);
  hipMemsetAsync(out, 0, (size_t)NATOMS * BATCH * sizeof(float), stream);
  ksvd_main<<<BATCH / BT, 512, 0, stream>>>(X, D, gram, out);
}